// Round 2
// baseline (1559.539 us; speedup 1.0000x reference)
//
#include <hip/hip_runtime.h>

// Problem constants (fixed by the reference)
#define B_    128
#define L_    1024
#define DK_   128
#define DV_   256
#define NS_   50      // N memory slots
#define H_    256
#define M_    (B_ * L_)   // 131072 rows

typedef __attribute__((ext_vector_type(8))) short   short8;
typedef __attribute__((ext_vector_type(4))) float   float4v;
typedef __attribute__((ext_vector_type(4))) int     int4v;

__device__ __forceinline__ float b2f(unsigned short u) {
    unsigned int x = ((unsigned int)u) << 16;
    return __builtin_bit_cast(float, x);
}
__device__ __forceinline__ unsigned short f2b(float f) {
    unsigned int x = __builtin_bit_cast(unsigned int, f);
    x += 0x7fffu + ((x >> 16) & 1u);   // round-to-nearest-even
    return (unsigned short)(x >> 16);
}
__device__ __forceinline__ int pack2(float lo, float hi) {
    return (int)f2b(lo) | ((int)f2b(hi) << 16);
}
__device__ __forceinline__ float sigmoid_f(float x) {
    return 1.f / (1.f + __expf(-x));
}
__device__ __forceinline__ float tanh_f(float x) {
    return 1.f - 2.f / (__expf(2.f * x) + 1.f);  // safe at exp overflow
}

// ---------------------------------------------------------------------------
// Gate kernel: e = sigmoid(X We^T + be), a = tanh(X Wa^T + ba)
// X: (M_,256) fp32. We/Wa: (256,256) fp32 row-major [out][in] = B^T layout.
// Outputs bf16. grid (M_/128, 2, 2)  block 256
// ---------------------------------------------------------------------------
__global__ __launch_bounds__(256) void gate_kernel(
    const float* __restrict__ X,
    const float* __restrict__ We, const float* __restrict__ be,
    const float* __restrict__ Wa, const float* __restrict__ ba,
    unsigned short* __restrict__ e_out, unsigned short* __restrict__ a_out)
{
    constexpr int K = DV_;  // 256
    const int mblk = blockIdx.x, nblk = blockIdx.y, gate = blockIdx.z;
    const float* W    = gate ? Wa : We;
    const float* bias = gate ? ba : be;
    unsigned short* out = gate ? a_out : e_out;

    __shared__ unsigned short As[128 * 40];  // +8 pad per row
    __shared__ unsigned short Bs[128 * 40];

    const int tid  = threadIdx.x;
    const int lane = tid & 63, wid = tid >> 6;
    const int wm = wid >> 1, wn = wid & 1;
    const int l15 = lane & 15, quad = lane >> 4;

    float4v acc[4][4];
#pragma unroll
    for (int i = 0; i < 4; i++)
#pragma unroll
        for (int j = 0; j < 4; j++) {
            acc[i][j][0] = 0.f; acc[i][j][1] = 0.f;
            acc[i][j][2] = 0.f; acc[i][j][3] = 0.f;
        }

    const int srow = tid >> 1;          // 0..127
    const int scol = (tid & 1) * 16;    // 0 or 16 (bf16 element units)
    const size_t Abase = ((size_t)mblk * 128 + srow) * K;
    const size_t Bbase = ((size_t)nblk * 128 + srow) * K;

    for (int k0 = 0; k0 < K; k0 += 32) {
        const float* xa = &X[Abase + k0 + scol];
        const float* xb = &W[Bbase + k0 + scol];
        int4v pa0, pa1, pb0, pb1;
#pragma unroll
        for (int j = 0; j < 4; j++) {
            pa0[j] = pack2(xa[2*j],     xa[2*j + 1]);
            pa1[j] = pack2(xa[2*j + 8], xa[2*j + 9]);
            pb0[j] = pack2(xb[2*j],     xb[2*j + 1]);
            pb1[j] = pack2(xb[2*j + 8], xb[2*j + 9]);
        }
        *(int4v*)&As[srow * 40 + scol]     = pa0;
        *(int4v*)&As[srow * 40 + scol + 8] = pa1;
        *(int4v*)&Bs[srow * 40 + scol]     = pb0;
        *(int4v*)&Bs[srow * 40 + scol + 8] = pb1;
        __syncthreads();
        short8 af[4], bf[4];
#pragma unroll
        for (int i = 0; i < 4; i++)
            af[i] = *(const short8*)&As[(64 * wm + 16 * i + l15) * 40 + quad * 8];
#pragma unroll
        for (int j = 0; j < 4; j++)
            bf[j] = *(const short8*)&Bs[(64 * wn + 16 * j + l15) * 40 + quad * 8];
#pragma unroll
        for (int i = 0; i < 4; i++)
#pragma unroll
            for (int j = 0; j < 4; j++)
                acc[i][j] = __builtin_amdgcn_mfma_f32_16x16x32_bf16(af[i], bf[j], acc[i][j], 0, 0, 0);
        __syncthreads();
    }

#pragma unroll
    for (int i = 0; i < 4; i++) {
        const int row = mblk * 128 + 64 * wm + 16 * i + quad * 4;
#pragma unroll
        for (int j = 0; j < 4; j++) {
            const int col = nblk * 128 + 64 * wn + 16 * j + l15;
            const float bv = bias[col];
#pragma unroll
            for (int r = 0; r < 4; r++) {
                float v = acc[i][j][r] + bv;
                v = gate ? tanh_f(v) : sigmoid_f(v);
                out[(size_t)(row + r) * DV_ + col] = f2b(v);
            }
        }
    }
}

// ---------------------------------------------------------------------------
// Score kernel: score = softmax(P Wk^T) over 50 slots. Thread per row. fp32.
// grid 512, block 256
// ---------------------------------------------------------------------------
__global__ __launch_bounds__(256) void score_kernel(
    const float* __restrict__ problems,  // (M_,128)
    const float* __restrict__ w_key,     // (50,128)
    float* __restrict__ score)           // (M_,50)
{
    const int rowi = blockIdx.x * 256 + threadIdx.x;
    const float* p = problems + (size_t)rowi * DK_;

    float logit[NS_];
#pragma unroll
    for (int n = 0; n < NS_; n++) logit[n] = 0.f;

    for (int k0 = 0; k0 < DK_; k0 += 4) {
        float pf0 = p[k0], pf1 = p[k0+1], pf2 = p[k0+2], pf3 = p[k0+3];
#pragma unroll
        for (int n = 0; n < NS_; n++) {
            const float* wk = &w_key[n * DK_ + k0];   // wave-uniform -> s_load
            logit[n] += pf0 * wk[0] + pf1 * wk[1] + pf2 * wk[2] + pf3 * wk[3];
        }
    }

    float mx = logit[0];
#pragma unroll
    for (int n = 1; n < NS_; n++) mx = fmaxf(mx, logit[n]);
    float sum = 0.f;
#pragma unroll
    for (int n = 0; n < NS_; n++) { logit[n] = __expf(logit[n] - mx); sum += logit[n]; }
    const float inv = 1.f / sum;
    float* o = score + (size_t)rowi * NS_;
#pragma unroll
    for (int n = 0; n < NS_; n++) o[n] = logit[n] * inv;
}

// ---------------------------------------------------------------------------
// Scan kernel: sequential over t; memory column in registers.
// grid (2, 128)  block 128.  d = blockIdx.x*128 + tid; b = blockIdx.y
// ---------------------------------------------------------------------------
__global__ __launch_bounds__(128) void scan_kernel(
    const float* __restrict__ score,              // (M_,50) fp32
    const unsigned short* __restrict__ e_buf,     // (M_,256) bf16
    const unsigned short* __restrict__ a_buf,     // (M_,256) bf16
    const float* __restrict__ init_mem,           // (50,256) fp32
    unsigned short* __restrict__ reads)           // (M_,256) bf16
{
    const int b = blockIdx.y;
    const int d = blockIdx.x * 128 + threadIdx.x;

    float M[NS_];
#pragma unroll
    for (int n = 0; n < NS_; n++) M[n] = init_mem[n * DV_ + d];

    const size_t rb = (size_t)b * L_;
    const unsigned short* ep = e_buf + rb * DV_ + d;
    const unsigned short* ap = a_buf + rb * DV_ + d;
    unsigned short*       rp = reads + rb * DV_ + d;
    const float*         scp = score + rb * NS_;   // block-uniform -> scalar loads

    float e_cur = b2f(ep[0]);
    float a_cur = b2f(ap[0]);

    for (int t = 0; t < L_; t++) {
        float e_nxt = 0.f, a_nxt = 0.f;
        if (t + 1 < L_) {
            e_nxt = b2f(ep[(size_t)(t + 1) * DV_]);
            a_nxt = b2f(ap[(size_t)(t + 1) * DV_]);
        }
        const float* sc = scp + (size_t)t * NS_;
        float r0 = 0.f, r1 = 0.f, r2 = 0.f, r3 = 0.f;
#pragma unroll
        for (int n = 0; n < 48; n += 4) {
            const float s0 = sc[n], s1 = sc[n + 1], s2 = sc[n + 2], s3 = sc[n + 3];
            r0 += s0 * M[n];     M[n]     += s0 * (a_cur - e_cur * M[n]);
            r1 += s1 * M[n + 1]; M[n + 1] += s1 * (a_cur - e_cur * M[n + 1]);
            r2 += s2 * M[n + 2]; M[n + 2] += s2 * (a_cur - e_cur * M[n + 2]);
            r3 += s3 * M[n + 3]; M[n + 3] += s3 * (a_cur - e_cur * M[n + 3]);
        }
        {
            const float s0 = sc[48], s1 = sc[49];
            r0 += s0 * M[48]; M[48] += s0 * (a_cur - e_cur * M[48]);
            r1 += s1 * M[49]; M[49] += s1 * (a_cur - e_cur * M[49]);
        }
        rp[(size_t)t * DV_] = f2b((r0 + r1) + (r2 + r3));
        e_cur = e_nxt; a_cur = a_nxt;
    }
}

// ---------------------------------------------------------------------------
// Output kernel: out = tanh([reads | problems] Wo^T + bo), fp32 out
// K = 384 (256 reads bf16 + 128 problems fp32). grid (M_/128, 2) block 256
// ---------------------------------------------------------------------------
__global__ __launch_bounds__(256) void out_kernel(
    const unsigned short* __restrict__ reads,  // (M_,256) bf16
    const float* __restrict__ problems,        // (M_,128) fp32
    const float* __restrict__ Wo,              // (256,384) fp32
    const float* __restrict__ bo,              // (256) fp32
    float* __restrict__ out)                   // (M_,256) fp32
{
    constexpr int K = DV_ + DK_;  // 384
    const int mblk = blockIdx.x, nblk = blockIdx.y;

    __shared__ unsigned short As[128 * 40];
    __shared__ unsigned short Bs[128 * 40];

    const int tid  = threadIdx.x;
    const int lane = tid & 63, wid = tid >> 6;
    const int wm = wid >> 1, wn = wid & 1;
    const int l15 = lane & 15, quad = lane >> 4;

    float4v acc[4][4];
#pragma unroll
    for (int i = 0; i < 4; i++)
#pragma unroll
        for (int j = 0; j < 4; j++) {
            acc[i][j][0] = 0.f; acc[i][j][1] = 0.f;
            acc[i][j][2] = 0.f; acc[i][j][3] = 0.f;
        }

    const int srow = tid >> 1;
    const int scol = (tid & 1) * 16;
    const size_t mrow = (size_t)mblk * 128 + srow;
    const size_t brow = (size_t)nblk * 128 + srow;

    for (int k0 = 0; k0 < K; k0 += 32) {
        const int kk = k0 + scol;
        int4v a0, a1;
        if (kk < DV_) {  // reads, already bf16
            a0 = *(const int4v*)&reads[mrow * DV_ + kk];
            a1 = *(const int4v*)&reads[mrow * DV_ + kk + 8];
        } else {         // problems, fp32 -> bf16
            const float* pr = &problems[mrow * DK_ + (kk - DV_)];
#pragma unroll
            for (int j = 0; j < 4; j++) {
                a0[j] = pack2(pr[2*j],     pr[2*j + 1]);
                a1[j] = pack2(pr[2*j + 8], pr[2*j + 9]);
            }
        }
        const float* wb = &Wo[brow * K + kk];
        int4v b0, b1;
#pragma unroll
        for (int j = 0; j < 4; j++) {
            b0[j] = pack2(wb[2*j],     wb[2*j + 1]);
            b1[j] = pack2(wb[2*j + 8], wb[2*j + 9]);
        }
        *(int4v*)&As[srow * 40 + scol]     = a0;
        *(int4v*)&As[srow * 40 + scol + 8] = a1;
        *(int4v*)&Bs[srow * 40 + scol]     = b0;
        *(int4v*)&Bs[srow * 40 + scol + 8] = b1;
        __syncthreads();
        short8 af[4], bf[4];
#pragma unroll
        for (int i = 0; i < 4; i++)
            af[i] = *(const short8*)&As[(64 * wm + 16 * i + l15) * 40 + quad * 8];
#pragma unroll
        for (int j = 0; j < 4; j++)
            bf[j] = *(const short8*)&Bs[(64 * wn + 16 * j + l15) * 40 + quad * 8];
#pragma unroll
        for (int i = 0; i < 4; i++)
#pragma unroll
            for (int j = 0; j < 4; j++)
                acc[i][j] = __builtin_amdgcn_mfma_f32_16x16x32_bf16(af[i], bf[j], acc[i][j], 0, 0, 0);
        __syncthreads();
    }

#pragma unroll
    for (int i = 0; i < 4; i++) {
        const int row = mblk * 128 + 64 * wm + 16 * i + quad * 4;
#pragma unroll
        for (int j = 0; j < 4; j++) {
            const int col = nblk * 128 + 64 * wn + 16 * j + l15;
            const float bv = bo[col];
#pragma unroll
            for (int r = 0; r < 4; r++) {
                out[(size_t)(row + r) * H_ + col] = tanh_f(acc[i][j][r] + bv);
            }
        }
    }
}

// ---------------------------------------------------------------------------
extern "C" void kernel_launch(void* const* d_in, const int* in_sizes, int n_in,
                              void* d_out, int out_size, void* d_ws, size_t ws_size,
                              hipStream_t stream) {
    const float* problems  = (const float*)d_in[0];
    const float* interact  = (const float*)d_in[1];
    const float* w_key     = (const float*)d_in[2];
    const float* w_erase_w = (const float*)d_in[3];
    const float* w_erase_b = (const float*)d_in[4];
    const float* w_add_w   = (const float*)d_in[5];
    const float* w_add_b   = (const float*)d_in[6];
    const float* w_out_w   = (const float*)d_in[7];
    const float* w_out_b   = (const float*)d_in[8];
    const float* init_mem  = (const float*)d_in[9];

    // workspace layout (bytes): e (64MB bf16) | a (64MB bf16) | reads (64MB bf16) | score (25MB fp32)
    char* ws = (char*)d_ws;
    const size_t SZ_BF = (size_t)M_ * DV_ * 2;   // 67,108,864
    unsigned short* e_buf = (unsigned short*)(ws);
    unsigned short* a_buf = (unsigned short*)(ws + SZ_BF);
    unsigned short* reads = (unsigned short*)(ws + 2 * SZ_BF);
    float*          score = (float*)(ws + 3 * SZ_BF);

    gate_kernel<<<dim3(M_ / 128, DV_ / 128, 2), 256, 0, stream>>>(
        interact, w_erase_w, w_erase_b, w_add_w, w_add_b, e_buf, a_buf);

    score_kernel<<<M_ / 256, 256, 0, stream>>>(problems, w_key, score);

    scan_kernel<<<dim3(DV_ / 128, B_), 128, 0, stream>>>(
        score, e_buf, a_buf, init_mem, reads);

    out_kernel<<<dim3(M_ / 128, H_ / 128), 256, 0, stream>>>(
        reads, problems, w_out_w, w_out_b, (float*)d_out);
}

// Round 3
// 1188.946 us; speedup vs baseline: 1.3117x; 1.3117x over previous
//
#include <hip/hip_runtime.h>

// Problem constants (fixed by the reference)
#define B_    128
#define L_    1024
#define DK_   128
#define DV_   256
#define NS_   50      // N memory slots
#define H_    256
#define M_    (B_ * L_)   // 131072 rows

typedef __attribute__((ext_vector_type(8))) short   short8;
typedef __attribute__((ext_vector_type(4))) float   float4v;
typedef __attribute__((ext_vector_type(4))) int     int4v;

__device__ __forceinline__ float b2f(unsigned short u) {
    unsigned int x = ((unsigned int)u) << 16;
    return __builtin_bit_cast(float, x);
}
__device__ __forceinline__ unsigned short f2b(float f) {
    unsigned int x = __builtin_bit_cast(unsigned int, f);
    x += 0x7fffu + ((x >> 16) & 1u);   // round-to-nearest-even
    return (unsigned short)(x >> 16);
}
__device__ __forceinline__ int pack2(float lo, float hi) {
    return (int)f2b(lo) | ((int)f2b(hi) << 16);
}
__device__ __forceinline__ float sigmoid_f(float x) {
    return 1.f / (1.f + __expf(-x));
}
__device__ __forceinline__ float tanh_f(float x) {
    return 1.f - 2.f / (__expf(2.f * x) + 1.f);  // safe at exp overflow
}

// ---------------------------------------------------------------------------
// Gate kernel: e = sigmoid(X We^T + be), a = tanh(X Wa^T + ba)
// X: (M_,256) fp32. We/Wa: (256,256) fp32 row-major [out][in] = B^T layout.
// Outputs bf16. grid (M_/128, 2, 2)  block 256
// ---------------------------------------------------------------------------
__global__ __launch_bounds__(256) void gate_kernel(
    const float* __restrict__ X,
    const float* __restrict__ We, const float* __restrict__ be,
    const float* __restrict__ Wa, const float* __restrict__ ba,
    unsigned short* __restrict__ e_out, unsigned short* __restrict__ a_out)
{
    constexpr int K = DV_;  // 256
    const int mblk = blockIdx.x, nblk = blockIdx.y, gate = blockIdx.z;
    const float* W    = gate ? Wa : We;
    const float* bias = gate ? ba : be;
    unsigned short* out = gate ? a_out : e_out;

    __shared__ unsigned short As[128 * 40];  // +8 pad per row
    __shared__ unsigned short Bs[128 * 40];

    const int tid  = threadIdx.x;
    const int lane = tid & 63, wid = tid >> 6;
    const int wm = wid >> 1, wn = wid & 1;
    const int l15 = lane & 15, quad = lane >> 4;

    float4v acc[4][4];
#pragma unroll
    for (int i = 0; i < 4; i++)
#pragma unroll
        for (int j = 0; j < 4; j++) {
            acc[i][j][0] = 0.f; acc[i][j][1] = 0.f;
            acc[i][j][2] = 0.f; acc[i][j][3] = 0.f;
        }

    const int srow = tid >> 1;          // 0..127
    const int scol = (tid & 1) * 16;    // 0 or 16 (bf16 element units)
    const size_t Abase = ((size_t)mblk * 128 + srow) * K;
    const size_t Bbase = ((size_t)nblk * 128 + srow) * K;

    for (int k0 = 0; k0 < K; k0 += 32) {
        const float* xa = &X[Abase + k0 + scol];
        const float* xb = &W[Bbase + k0 + scol];
        int4v pa0, pa1, pb0, pb1;
#pragma unroll
        for (int j = 0; j < 4; j++) {
            pa0[j] = pack2(xa[2*j],     xa[2*j + 1]);
            pa1[j] = pack2(xa[2*j + 8], xa[2*j + 9]);
            pb0[j] = pack2(xb[2*j],     xb[2*j + 1]);
            pb1[j] = pack2(xb[2*j + 8], xb[2*j + 9]);
        }
        *(int4v*)&As[srow * 40 + scol]     = pa0;
        *(int4v*)&As[srow * 40 + scol + 8] = pa1;
        *(int4v*)&Bs[srow * 40 + scol]     = pb0;
        *(int4v*)&Bs[srow * 40 + scol + 8] = pb1;
        __syncthreads();
        short8 af[4], bf[4];
#pragma unroll
        for (int i = 0; i < 4; i++)
            af[i] = *(const short8*)&As[(64 * wm + 16 * i + l15) * 40 + quad * 8];
#pragma unroll
        for (int j = 0; j < 4; j++)
            bf[j] = *(const short8*)&Bs[(64 * wn + 16 * j + l15) * 40 + quad * 8];
#pragma unroll
        for (int i = 0; i < 4; i++)
#pragma unroll
            for (int j = 0; j < 4; j++)
                acc[i][j] = __builtin_amdgcn_mfma_f32_16x16x32_bf16(af[i], bf[j], acc[i][j], 0, 0, 0);
        __syncthreads();
    }

#pragma unroll
    for (int i = 0; i < 4; i++) {
        const int row = mblk * 128 + 64 * wm + 16 * i + quad * 4;
#pragma unroll
        for (int j = 0; j < 4; j++) {
            const int col = nblk * 128 + 64 * wn + 16 * j + l15;
            const float bv = bias[col];
#pragma unroll
            for (int r = 0; r < 4; r++) {
                float v = acc[i][j][r] + bv;
                v = gate ? tanh_f(v) : sigmoid_f(v);
                out[(size_t)(row + r) * DV_ + col] = f2b(v);
            }
        }
    }
}

// ---------------------------------------------------------------------------
// Score kernel: score = softmax(P Wk^T) over 50 slots. Thread per row. fp32.
// Emits scan-friendly layout: (B, L, 4, 16) fp32, slot n = ng*13+i at
// [ng*16 + i] for i<13 (and n<50); padding zeros elsewhere.
// grid 512, block 256
// ---------------------------------------------------------------------------
__global__ __launch_bounds__(256) void score_kernel(
    const float* __restrict__ problems,  // (M_,128)
    const float* __restrict__ w_key,     // (50,128)
    float* __restrict__ score_scan)      // (M_,64)
{
    const int rowi = blockIdx.x * 256 + threadIdx.x;
    const float* p = problems + (size_t)rowi * DK_;

    float logit[NS_];
#pragma unroll
    for (int n = 0; n < NS_; n++) logit[n] = 0.f;

    for (int k0 = 0; k0 < DK_; k0 += 4) {
        float pf0 = p[k0], pf1 = p[k0+1], pf2 = p[k0+2], pf3 = p[k0+3];
#pragma unroll
        for (int n = 0; n < NS_; n++) {
            const float* wk = &w_key[n * DK_ + k0];   // wave-uniform -> s_load
            logit[n] += pf0 * wk[0] + pf1 * wk[1] + pf2 * wk[2] + pf3 * wk[3];
        }
    }

    float mx = logit[0];
#pragma unroll
    for (int n = 1; n < NS_; n++) mx = fmaxf(mx, logit[n]);
    float sum = 0.f;
#pragma unroll
    for (int n = 0; n < NS_; n++) { logit[n] = __expf(logit[n] - mx); sum += logit[n]; }
    const float inv = 1.f / sum;

    float* o = score_scan + (size_t)rowi * 64;
#pragma unroll
    for (int v = 0; v < 16; v++) {
        float4v st;
#pragma unroll
        for (int c = 0; c < 4; c++) {
            const int j  = v * 4 + c;
            const int ng = j >> 4, ii = j & 15;
            const int n  = ng * 13 + ii;
            st[c] = (ii < 13 && n < NS_) ? logit[n] * inv : 0.f;
        }
        *(float4v*)(o + v * 4) = st;
    }
}

// ---------------------------------------------------------------------------
// Scan kernel v2: lane = (d_sub 0..15) + 16*(n-group 0..3); 13 slots/lane.
// Read-reduce via 2 butterfly shuffles; all loads prefetched 1 step ahead.
// grid (4, 128)  block 256.
// ---------------------------------------------------------------------------
__global__ __launch_bounds__(256) void scan_kernel(
    const float* __restrict__ score_scan,         // (M_,64) fp32, zero-padded
    const unsigned short* __restrict__ e_buf,     // (M_,256) bf16
    const unsigned short* __restrict__ a_buf,     // (M_,256) bf16
    const float* __restrict__ init_mem,           // (50,256) fp32
    unsigned short* __restrict__ reads)           // (M_,256) bf16
{
    const int b    = blockIdx.y;
    const int dblk = blockIdx.x;          // 0..3
    const int tid  = threadIdx.x;
    const int w    = tid >> 6;
    const int lane = tid & 63;
    const int dsub = lane & 15;
    const int ng   = lane >> 4;
    const int d    = dblk * 64 + w * 16 + dsub;

    float M[13];
#pragma unroll
    for (int i = 0; i < 13; i++) {
        const int n = ng * 13 + i;
        M[i] = (n < NS_) ? init_mem[n * DV_ + d] : 0.f;
    }

    const size_t rb = (size_t)b * L_;
    const float* scp = score_scan + rb * 64 + ng * 16;
    const unsigned short* ep = e_buf + rb * DV_ + d;
    const unsigned short* ap = a_buf + rb * DV_ + d;
    unsigned short*       rp = reads + rb * DV_ + d;

    // prefetch t = 0
    float4v s0 = *(const float4v*)(scp);
    float4v s1 = *(const float4v*)(scp + 4);
    float4v s2 = *(const float4v*)(scp + 8);
    float   s3 = scp[12];
    float e_cur = b2f(ep[0]);
    float a_cur = b2f(ap[0]);

    for (int t = 0; t < L_; t++) {
        // issue t+1 loads before t's compute (clamped on last iter; values unused)
        const int tn = (t + 1 < L_) ? (t + 1) : (L_ - 1);
        const float* scn = scp + (size_t)tn * 64;
        float4v n0 = *(const float4v*)(scn);
        float4v n1 = *(const float4v*)(scn + 4);
        float4v n2 = *(const float4v*)(scn + 8);
        float   n3 = scn[12];
        const float e_nxt = b2f(ep[(size_t)tn * DV_]);
        const float a_nxt = b2f(ap[(size_t)tn * DV_]);

        float r = 0.f;
        const float sarr[13] = { s0[0], s0[1], s0[2], s0[3],
                                 s1[0], s1[1], s1[2], s1[3],
                                 s2[0], s2[1], s2[2], s2[3], s3 };
#pragma unroll
        for (int i = 0; i < 13; i++) {
            const float s = sarr[i];
            r = fmaf(s, M[i], r);                       // read BEFORE update
            M[i] = fmaf(s, fmaf(-e_cur, M[i], a_cur), M[i]);
        }
        // reduce partial reads across the 4 n-groups (lanes differing in bits 4,5)
        r += __shfl_xor(r, 16);
        r += __shfl_xor(r, 32);
        if (ng == 0) rp[(size_t)t * DV_] = f2b(r);

        s0 = n0; s1 = n1; s2 = n2; s3 = n3;
        e_cur = e_nxt; a_cur = a_nxt;
    }
}

// ---------------------------------------------------------------------------
// Output kernel: out = tanh([reads | problems] Wo^T + bo), fp32 out
// K = 384 (256 reads bf16 + 128 problems fp32). grid (M_/128, 2) block 256
// ---------------------------------------------------------------------------
__global__ __launch_bounds__(256) void out_kernel(
    const unsigned short* __restrict__ reads,  // (M_,256) bf16
    const float* __restrict__ problems,        // (M_,128) fp32
    const float* __restrict__ Wo,              // (256,384) fp32
    const float* __restrict__ bo,              // (256) fp32
    float* __restrict__ out)                   // (M_,256) fp32
{
    constexpr int K = DV_ + DK_;  // 384
    const int mblk = blockIdx.x, nblk = blockIdx.y;

    __shared__ unsigned short As[128 * 40];
    __shared__ unsigned short Bs[128 * 40];

    const int tid  = threadIdx.x;
    const int lane = tid & 63, wid = tid >> 6;
    const int wm = wid >> 1, wn = wid & 1;
    const int l15 = lane & 15, quad = lane >> 4;

    float4v acc[4][4];
#pragma unroll
    for (int i = 0; i < 4; i++)
#pragma unroll
        for (int j = 0; j < 4; j++) {
            acc[i][j][0] = 0.f; acc[i][j][1] = 0.f;
            acc[i][j][2] = 0.f; acc[i][j][3] = 0.f;
        }

    const int srow = tid >> 1;
    const int scol = (tid & 1) * 16;
    const size_t mrow = (size_t)mblk * 128 + srow;
    const size_t brow = (size_t)nblk * 128 + srow;

    for (int k0 = 0; k0 < K; k0 += 32) {
        const int kk = k0 + scol;
        int4v a0, a1;
        if (kk < DV_) {  // reads, already bf16
            a0 = *(const int4v*)&reads[mrow * DV_ + kk];
            a1 = *(const int4v*)&reads[mrow * DV_ + kk + 8];
        } else {         // problems, fp32 -> bf16
            const float* pr = &problems[mrow * DK_ + (kk - DV_)];
#pragma unroll
            for (int j = 0; j < 4; j++) {
                a0[j] = pack2(pr[2*j],     pr[2*j + 1]);
                a1[j] = pack2(pr[2*j + 8], pr[2*j + 9]);
            }
        }
        const float* wb = &Wo[brow * K + kk];
        int4v b0, b1;
#pragma unroll
        for (int j = 0; j < 4; j++) {
            b0[j] = pack2(wb[2*j],     wb[2*j + 1]);
            b1[j] = pack2(wb[2*j + 8], wb[2*j + 9]);
        }
        *(int4v*)&As[srow * 40 + scol]     = a0;
        *(int4v*)&As[srow * 40 + scol + 8] = a1;
        *(int4v*)&Bs[srow * 40 + scol]     = b0;
        *(int4v*)&Bs[srow * 40 + scol + 8] = b1;
        __syncthreads();
        short8 af[4], bf[4];
#pragma unroll
        for (int i = 0; i < 4; i++)
            af[i] = *(const short8*)&As[(64 * wm + 16 * i + l15) * 40 + quad * 8];
#pragma unroll
        for (int j = 0; j < 4; j++)
            bf[j] = *(const short8*)&Bs[(64 * wn + 16 * j + l15) * 40 + quad * 8];
#pragma unroll
        for (int i = 0; i < 4; i++)
#pragma unroll
            for (int j = 0; j < 4; j++)
                acc[i][j] = __builtin_amdgcn_mfma_f32_16x16x32_bf16(af[i], bf[j], acc[i][j], 0, 0, 0);
        __syncthreads();
    }

#pragma unroll
    for (int i = 0; i < 4; i++) {
        const int row = mblk * 128 + 64 * wm + 16 * i + quad * 4;
#pragma unroll
        for (int j = 0; j < 4; j++) {
            const int col = nblk * 128 + 64 * wn + 16 * j + l15;
            const float bv = bo[col];
#pragma unroll
            for (int r = 0; r < 4; r++) {
                out[(size_t)(row + r) * H_ + col] = tanh_f(acc[i][j][r] + bv);
            }
        }
    }
}

// ---------------------------------------------------------------------------
extern "C" void kernel_launch(void* const* d_in, const int* in_sizes, int n_in,
                              void* d_out, int out_size, void* d_ws, size_t ws_size,
                              hipStream_t stream) {
    const float* problems  = (const float*)d_in[0];
    const float* interact  = (const float*)d_in[1];
    const float* w_key     = (const float*)d_in[2];
    const float* w_erase_w = (const float*)d_in[3];
    const float* w_erase_b = (const float*)d_in[4];
    const float* w_add_w   = (const float*)d_in[5];
    const float* w_add_b   = (const float*)d_in[6];
    const float* w_out_w   = (const float*)d_in[7];
    const float* w_out_b   = (const float*)d_in[8];
    const float* init_mem  = (const float*)d_in[9];

    // workspace: e (64MB bf16) | a (64MB bf16) | reads (64MB bf16) | score_scan (33.5MB fp32)
    char* ws = (char*)d_ws;
    const size_t SZ_BF = (size_t)M_ * DV_ * 2;   // 67,108,864
    unsigned short* e_buf = (unsigned short*)(ws);
    unsigned short* a_buf = (unsigned short*)(ws + SZ_BF);
    unsigned short* reads = (unsigned short*)(ws + 2 * SZ_BF);
    float*     score_scan = (float*)(ws + 3 * SZ_BF);

    gate_kernel<<<dim3(M_ / 128, DV_ / 128, 2), 256, 0, stream>>>(
        interact, w_erase_w, w_erase_b, w_add_w, w_add_b, e_buf, a_buf);

    score_kernel<<<M_ / 256, 256, 0, stream>>>(problems, w_key, score_scan);

    scan_kernel<<<dim3(4, B_), 256, 0, stream>>>(
        score_scan, e_buf, a_buf, init_mem, reads);

    out_kernel<<<dim3(M_ / 128, H_ / 128), 256, 0, stream>>>(
        reads, problems, w_out_w, w_out_b, (float*)d_out);
}